// Round 2
// baseline (405.222 us; speedup 1.0000x reference)
//
#include <hip/hip_runtime.h>
#include <math.h>

// LayerNorm_v2: B=8, S=4096, D=1024, f32 in / f32 out.
// Reference quirks replicated:
//  - stats from batch 0 only, broadcast over all batches
//  - "buggy Welford": mean_k=(mean_{k-1}+d_k)/k ; var += (d_k-mean_k)^2 ; var/=(D-1)
//
// v3: SINGLE fused kernel. Block s owns row s: computes stats from batch-0
// row s (one wave, lane L owns elements 16L..16L+15), normalizes batch 0
// straight from registers, then streams batches 1..7 with a depth-2
// pipeline. No workspace, no second launch, no inter-kernel drain; the
// batch-1 loads are issued BEFORE the stats ALU chain so the serial
// recurrence hides under memory latency.
#define BB 8
#define SS 4096
#define DD 1024
#define EPSF 1e-5f

typedef float f32x4 __attribute__((ext_vector_type(4)));

__global__ __launch_bounds__(64) void fused_ln_kernel(
    const float* __restrict__ x,
    const float* __restrict__ alpha,
    const float* __restrict__ beta,
    float* __restrict__ out)
{
    const int row = blockIdx.x;           // 0..4095
    const int L   = threadIdx.x;          // 0..63; lane L owns k in [16L+1, 16L+16]
    const size_t row4   = (size_t)row * (DD / 4);   // float4 offset of row in a batch
    const size_t batch4 = (size_t)SS * (DD / 4);    // float4 per batch

    const f32x4*  __restrict__ xp   = reinterpret_cast<const f32x4*>(x);
    f32x4*        __restrict__ op   = reinterpret_cast<f32x4*>(out);
    const float4* __restrict__ rowp = reinterpret_cast<const float4*>(x) + row4;

    // ---- batch-0 row: own 16 floats (float4 slots 4L..4L+3) ----
    const float4 a0 = rowp[4 * L + 0];
    const float4 a1 = rowp[4 * L + 1];
    const float4 a2 = rowp[4 * L + 2];
    const float4 a3 = rowp[4 * L + 3];
    const float d[16] = { a0.x, a0.y, a0.z, a0.w,  a1.x, a1.y, a1.z, a1.w,
                          a2.x, a2.y, a2.z, a2.w,  a3.x, a3.y, a3.z, a3.w };

    // Seed loads (2 float4 just below this lane's span).
    float4 p0 = {0,0,0,0}, p1 = {0,0,0,0};
    if (L > 0) {
        p0 = rowp[4 * L - 2];   // floats 16L-8 .. 16L-5
        p1 = rowp[4 * L - 1];   // floats 16L-4 .. 16L-1
    }

    // ---- issue batch-1 loads + alpha/beta loads EARLY (independent of stats)
    const size_t b1 = batch4 + row4;
    f32x4 cur[4];
#pragma unroll
    for (int q = 0; q < 4; ++q)
        cur[q] = __builtin_nontemporal_load(xp + b1 + 4 * L + q);

    const float4* __restrict__ alpha4 = reinterpret_cast<const float4*>(alpha);
    const float4* __restrict__ beta4  = reinterpret_cast<const float4*>(beta);
    float4 av[4], bv[4];
#pragma unroll
    for (int q = 0; q < 4; ++q) { av[q] = alpha4[4 * L + q]; bv[q] = beta4[4 * L + q]; }

    // ---- stats: seed mean_{16L} via 6-term Horner series, then 16 exact steps
    float m = 0.0f;
    if (L > 0) {
        const float jf = (float)(16 * L);
        float acc = p0.z;                                          // arr[j-6]
        acc = fmaf(acc, __builtin_amdgcn_rcpf(jf - 5.0f), p0.w);   // arr[j-5] + acc/(j-5)
        acc = fmaf(acc, __builtin_amdgcn_rcpf(jf - 4.0f), p1.x);
        acc = fmaf(acc, __builtin_amdgcn_rcpf(jf - 3.0f), p1.y);
        acc = fmaf(acc, __builtin_amdgcn_rcpf(jf - 2.0f), p1.z);
        acc = fmaf(acc, __builtin_amdgcn_rcpf(jf - 1.0f), p1.w);
        m = acc * __builtin_amdgcn_rcpf(jf);
    }

    float var = 0.0f;
    const float base = (float)(16 * L);
#pragma unroll
    for (int t = 0; t < 16; ++t) {
        const float rk = __builtin_amdgcn_rcpf(base + (float)(t + 1));  // 1/k
        m = (m + d[t]) * rk;
        const float df = d[t] - m;
        var = fmaf(df, df, var);
    }

    // Butterfly reduction: every lane ends with the full var sum.
#pragma unroll
    for (int off = 32; off >= 1; off >>= 1) var += __shfl_xor(var, off, 64);
    const float mf = __shfl(m, 63, 64);              // mean_1024 broadcast
    const float r  = rsqrtf(var * (1.0f / 1023.0f) + EPSF);

    // ---- normalize batch 0 from registers
#pragma unroll
    for (int q = 0; q < 4; ++q) {
        f32x4 o;
        o.x = fmaf(av[q].x * (d[4 * q + 0] - mf), r, bv[q].x);
        o.y = fmaf(av[q].y * (d[4 * q + 1] - mf), r, bv[q].y);
        o.z = fmaf(av[q].z * (d[4 * q + 2] - mf), r, bv[q].z);
        o.w = fmaf(av[q].w * (d[4 * q + 3] - mf), r, bv[q].w);
        __builtin_nontemporal_store(o, op + row4 + 4 * L + q);
    }

    // ---- stream batches 1..7, depth-2 pipeline (load b+1 before storing b)
    size_t cb = b1;                                  // current batch base
#pragma unroll
    for (int b = 1; b <= 6; ++b) {
        f32x4 nxt[4];
#pragma unroll
        for (int q = 0; q < 4; ++q)
            nxt[q] = __builtin_nontemporal_load(xp + cb + batch4 + 4 * L + q);
#pragma unroll
        for (int q = 0; q < 4; ++q) {
            f32x4 o;
            o.x = fmaf(av[q].x * (cur[q].x - mf), r, bv[q].x);
            o.y = fmaf(av[q].y * (cur[q].y - mf), r, bv[q].y);
            o.z = fmaf(av[q].z * (cur[q].z - mf), r, bv[q].z);
            o.w = fmaf(av[q].w * (cur[q].w - mf), r, bv[q].w);
            __builtin_nontemporal_store(o, op + cb + 4 * L + q);
        }
#pragma unroll
        for (int q = 0; q < 4; ++q) cur[q] = nxt[q];
        cb += batch4;
    }
    // epilogue: batch 7
#pragma unroll
    for (int q = 0; q < 4; ++q) {
        f32x4 o;
        o.x = fmaf(av[q].x * (cur[q].x - mf), r, bv[q].x);
        o.y = fmaf(av[q].y * (cur[q].y - mf), r, bv[q].y);
        o.z = fmaf(av[q].z * (cur[q].z - mf), r, bv[q].z);
        o.w = fmaf(av[q].w * (cur[q].w - mf), r, bv[q].w);
        __builtin_nontemporal_store(o, op + cb + 4 * L + q);
    }
}

extern "C" void kernel_launch(void* const* d_in, const int* in_sizes, int n_in,
                              void* d_out, int out_size, void* d_ws, size_t ws_size,
                              hipStream_t stream) {
    (void)in_sizes; (void)n_in; (void)out_size; (void)d_ws; (void)ws_size;
    const float* x     = (const float*)d_in[0];   // (8, 4096, 1024) f32
    const float* alpha = (const float*)d_in[1];   // (1024,) f32
    const float* beta  = (const float*)d_in[2];   // (1024,) f32
    float* out = (float*)d_out;

    hipLaunchKernelGGL(fused_ln_kernel, dim3(SS), dim3(64), 0, stream,
                       x, alpha, beta, out);
}

// Round 3
// 221.221 us; speedup vs baseline: 1.8318x; 1.8318x over previous
//
#include <hip/hip_runtime.h>
#include <math.h>

// LayerNorm_v2: B=8, S=4096, D=1024, f32 in / f32 out.
// Reference quirks replicated:
//  - stats from batch 0 only, broadcast over all batches
//  - "buggy Welford": mean_k=(mean_{k-1}+d_k)/k ; var += (d_k-mean_k)^2 ; var/=(D-1)
//
// v4: single fused kernel, COALESCED lane mapping (round-2's 64B-stride
// stores caused 2.5x write amplification @ 1.9 TB/s). Lane L owns float4
// slots L+64c (c=0..3): every load/store instruction is 64 lanes x 16 B
// contiguous = 1 KB. Stats run as 4 short recurrence chains per lane
// (chain c starts at j0=256c+4L), seeded by the 6-term closed-form series
// with the 6 preceding elements pulled from neighbor lanes via shuffles.
#define BB 8
#define SS 4096
#define DD 1024
#define EPSF 1e-5f

typedef float f32x4 __attribute__((ext_vector_type(4)));

__device__ __forceinline__ f32x4 shfl4(const f32x4 v, int lane) {
    f32x4 r;
    r.x = __shfl(v.x, lane, 64);
    r.y = __shfl(v.y, lane, 64);
    r.z = __shfl(v.z, lane, 64);
    r.w = __shfl(v.w, lane, 64);
    return r;
}
__device__ __forceinline__ f32x4 shfl4_up1(const f32x4 v) {
    f32x4 r;
    r.x = __shfl_up(v.x, 1, 64);
    r.y = __shfl_up(v.y, 1, 64);
    r.z = __shfl_up(v.z, 1, 64);
    r.w = __shfl_up(v.w, 1, 64);
    return r;
}

__global__ __launch_bounds__(256) void fused_ln_kernel(
    const float* __restrict__ x,
    const float* __restrict__ alpha,
    const float* __restrict__ beta,
    float* __restrict__ out)
{
    const int L   = threadIdx.x & 63;          // lane
    const int wv  = threadIdx.x >> 6;          // wave in block
    const int row = (blockIdx.x << 2) | wv;    // 0..4095, one row per wave
    const size_t row4   = (size_t)row * (DD / 4);
    const size_t batch4 = (size_t)SS * (DD / 4);

    const f32x4* __restrict__ xp = reinterpret_cast<const f32x4*>(x);
    f32x4*       __restrict__ op = reinterpret_cast<f32x4*>(out);

    // ---- batch-0 row, coalesced: lane L holds slots L+64c (floats 256c+4L..+3)
    f32x4 v[4];
#pragma unroll
    for (int c = 0; c < 4; ++c)
        v[c] = __builtin_nontemporal_load(xp + row4 + L + 64 * c);

    // ---- issue batch-1 + alpha/beta loads EARLY (independent of stats ALU)
    size_t cb = batch4 + row4;                 // current batch base (batch 1)
    f32x4 cur[4];
#pragma unroll
    for (int c = 0; c < 4; ++c)
        cur[c] = __builtin_nontemporal_load(xp + cb + L + 64 * c);

    const f32x4* __restrict__ a4 = reinterpret_cast<const f32x4*>(alpha);
    const f32x4* __restrict__ b4 = reinterpret_cast<const f32x4*>(beta);
    f32x4 av[4], bv[4];
#pragma unroll
    for (int c = 0; c < 4; ++c) { av[c] = a4[L + 64 * c]; bv[c] = b4[L + 64 * c]; }

    // ---- stats: 4 chains per lane; chain c covers k in [j0+1, j0+4], j0=256c+4L.
    // Seed mean_{j0} from the 6 preceding elements (closed-form factorial-decay
    // series, exact for the recurrence up to the dropped ~1/(j-6)! terms).
    float var    = 0.0f;
    float m_last = 0.0f;
#pragma unroll
    for (int c = 0; c < 4; ++c) {
        const f32x4 up1 = shfl4_up1(v[c]);                 // lane L-1's chunk c
        const float u2z = __shfl_up(v[c].z, 2, 64);        // lane L-2 .z
        const float u2w = __shfl_up(v[c].w, 2, 64);        // lane L-2 .w
        f32x4 wrap1 = {0.f, 0.f, 0.f, 0.f};
        float wz = 0.f, ww = 0.f;
        if (c > 0) {                                       // compile-time (unrolled)
            wrap1 = shfl4(v[c - 1], 63);                   // elements 256c-4..256c-1
            wz = __shfl(v[c - 1].z, 62, 64);               // element 256c-6
            ww = __shfl(v[c - 1].w, 62, 64);               // element 256c-5
        }

        const float jf = (float)(256 * c + 4 * L);         // j0
        float m;
        if (c == 0 && L == 0) {
            m = 0.0f;                                      // mean_0, exact
        } else if (c == 0 && L == 1) {
            // exact: mean_4 = d4/4 + d3/12 + (d2+d1)/24
            m = up1.w * 0.25f + up1.z * (1.0f / 12.0f)
              + (up1.y + up1.x) * (1.0f / 24.0f);
        } else {
            // window w0..w5 = elements j0-6..j0-1
            const f32x4 w25 = (L == 0) ? wrap1 : up1;      // w2..w5
            float w0, w1;
            if (L >= 2)      { w0 = u2z;     w1 = u2w;     }
            else if (L == 1) { w0 = wrap1.z; w1 = wrap1.w; }
            else             { w0 = wz;      w1 = ww;      }
            float acc = w0;
            acc = fmaf(acc, __builtin_amdgcn_rcpf(jf - 5.0f), w1);
            acc = fmaf(acc, __builtin_amdgcn_rcpf(jf - 4.0f), w25.x);
            acc = fmaf(acc, __builtin_amdgcn_rcpf(jf - 3.0f), w25.y);
            acc = fmaf(acc, __builtin_amdgcn_rcpf(jf - 2.0f), w25.z);
            acc = fmaf(acc, __builtin_amdgcn_rcpf(jf - 1.0f), w25.w);
            m = acc * __builtin_amdgcn_rcpf(jf);
        }

        const float dd[4] = { v[c].x, v[c].y, v[c].z, v[c].w };
#pragma unroll
        for (int t = 0; t < 4; ++t) {
            m = (m + dd[t]) * __builtin_amdgcn_rcpf(jf + (float)(t + 1));
            const float df = dd[t] - m;
            var = fmaf(df, df, var);
        }
        m_last = m;                                        // c=3 end = mean_1024
    }

    // Butterfly: every lane gets the full var; broadcast mean_1024 from lane 63.
#pragma unroll
    for (int off = 32; off >= 1; off >>= 1) var += __shfl_xor(var, off, 64);
    const float mf = __shfl(m_last, 63, 64);
    const float r  = rsqrtf(var * (1.0f / 1023.0f) + EPSF);

    // ---- normalize batch 0 straight from registers (coalesced stores)
#pragma unroll
    for (int c = 0; c < 4; ++c) {
        f32x4 o;
        o.x = fmaf(av[c].x * (v[c].x - mf), r, bv[c].x);
        o.y = fmaf(av[c].y * (v[c].y - mf), r, bv[c].y);
        o.z = fmaf(av[c].z * (v[c].z - mf), r, bv[c].z);
        o.w = fmaf(av[c].w * (v[c].w - mf), r, bv[c].w);
        __builtin_nontemporal_store(o, op + row4 + L + 64 * c);
    }

    // ---- stream batches 1..7, depth-2 pipeline (load b+1 before storing b)
#pragma unroll
    for (int b = 1; b <= 6; ++b) {
        f32x4 nxt[4];
#pragma unroll
        for (int c = 0; c < 4; ++c)
            nxt[c] = __builtin_nontemporal_load(xp + cb + batch4 + L + 64 * c);
#pragma unroll
        for (int c = 0; c < 4; ++c) {
            f32x4 o;
            o.x = fmaf(av[c].x * (cur[c].x - mf), r, bv[c].x);
            o.y = fmaf(av[c].y * (cur[c].y - mf), r, bv[c].y);
            o.z = fmaf(av[c].z * (cur[c].z - mf), r, bv[c].z);
            o.w = fmaf(av[c].w * (cur[c].w - mf), r, bv[c].w);
            __builtin_nontemporal_store(o, op + cb + L + 64 * c);
        }
#pragma unroll
        for (int c = 0; c < 4; ++c) cur[c] = nxt[c];
        cb += batch4;
    }
    // epilogue: batch 7
#pragma unroll
    for (int c = 0; c < 4; ++c) {
        f32x4 o;
        o.x = fmaf(av[c].x * (cur[c].x - mf), r, bv[c].x);
        o.y = fmaf(av[c].y * (cur[c].y - mf), r, bv[c].y);
        o.z = fmaf(av[c].z * (cur[c].z - mf), r, bv[c].z);
        o.w = fmaf(av[c].w * (cur[c].w - mf), r, bv[c].w);
        __builtin_nontemporal_store(o, op + cb + L + 64 * c);
    }
}

extern "C" void kernel_launch(void* const* d_in, const int* in_sizes, int n_in,
                              void* d_out, int out_size, void* d_ws, size_t ws_size,
                              hipStream_t stream) {
    (void)in_sizes; (void)n_in; (void)out_size; (void)d_ws; (void)ws_size;
    const float* x     = (const float*)d_in[0];   // (8, 4096, 1024) f32
    const float* alpha = (const float*)d_in[1];   // (1024,) f32
    const float* beta  = (const float*)d_in[2];   // (1024,) f32
    float* out = (float*)d_out;

    hipLaunchKernelGGL(fused_ln_kernel, dim3(SS / 4), dim3(256), 0, stream,
                       x, alpha, beta, out);
}